// Round 14
// baseline (166.350 us; speedup 1.0000x reference)
//
#include <hip/hip_runtime.h>
#include <hip/hip_bf16.h>

// Problem constants (B,T,C,H,DH) = (2,2048,768,12,64)
#define Bn 2
#define Tn 2048
#define Cn 768
#define Hn 12
#define Dn 64
#define N3n 2304
#define Mn 4096   // B*T

#define MASKVAL (-30000.f)   // finite sentinel; scores are O(+-40) unscaled
#define NIT_G 144            // items per XCD group: 48 sched entries * 3 (h,b)
#define DEFER_THR 64.f       // unscaled-score gap; P bounded by e^8
#define L2E8 0.1803368801111204f   // 0.125 * log2(e): exp(0.125*x) = exp2(L2E8*x)

typedef unsigned short u16;
typedef __attribute__((ext_vector_type(8))) unsigned short ushort8_t;
typedef __attribute__((ext_vector_type(8))) short bf16x8;   // 8 bf16 in 4 VGPRs
typedef __attribute__((ext_vector_type(4))) float f32x4;
typedef __attribute__((ext_vector_type(2))) unsigned int uint2v;  // 8B aligned
typedef __attribute__((address_space(1))) unsigned int* gas1_t;   // global
typedef __attribute__((address_space(3))) unsigned int* las3_t;   // LDS

__device__ __forceinline__ float bf2f(u16 u) {
  union { unsigned int i; float f; } v; v.i = ((unsigned int)u) << 16; return v.f;
}
__device__ __forceinline__ u16 f2bf(float f) {
  union { float f; unsigned int i; } v; v.f = f;
  return (u16)((v.i + 0x7fffu + ((v.i >> 16) & 1u)) >> 16);
}

// ---------------------------------------------------------------------------
// kv-split schedule, 128-wide kv steps. 48 entries, LPT order.
// entry = (qt<<24)|(s0<<16)|(s1<<8)|ck ; kv 128-steps [s0,s1) of q-tile qt.
// ck: 0/1 = split chunk id (writes partials), 2 = unsplit (direct O write).
// ---------------------------------------------------------------------------
#define E(qt, s0, s1, ck) (((qt) << 24) | ((s0) << 16) | ((s1) << 8) | (ck))
__constant__ unsigned int SCHED[48] = {
    // len 8
    E(31, 0, 8, 0), E(31, 8, 16, 1), E(30, 0, 8, 0), E(30, 8, 16, 1),
    E(29, 0, 8, 0), E(28, 0, 8, 0), E(15, 0, 8, 2), E(14, 0, 8, 2),
    // len 7
    E(29, 8, 15, 1), E(28, 8, 15, 1), E(27, 0, 7, 0), E(27, 7, 14, 1),
    E(26, 0, 7, 0), E(26, 7, 14, 1), E(25, 0, 7, 0), E(24, 0, 7, 0),
    E(13, 0, 7, 2), E(12, 0, 7, 2),
    // len 6
    E(25, 7, 13, 1), E(24, 7, 13, 1), E(23, 0, 6, 0), E(23, 6, 12, 1),
    E(22, 0, 6, 0), E(22, 6, 12, 1), E(21, 0, 6, 0), E(20, 0, 6, 0),
    E(11, 0, 6, 2), E(10, 0, 6, 2),
    // len 5
    E(21, 6, 11, 1), E(20, 6, 11, 1), E(19, 0, 5, 0), E(19, 5, 10, 1),
    E(18, 0, 5, 0), E(18, 5, 10, 1), E(17, 0, 5, 0), E(16, 0, 5, 0),
    E(9, 0, 5, 2), E(8, 0, 5, 2),
    // len 4
    E(17, 5, 9, 1), E(16, 5, 9, 1), E(7, 0, 4, 2), E(6, 0, 4, 2),
    // len 3..1
    E(5, 0, 3, 2), E(4, 0, 3, 2), E(3, 0, 2, 2), E(2, 0, 2, 2),
    E(1, 0, 1, 2), E(0, 0, 1, 2)};

// ---------------------------------------------------------------------------
// Prep (merged, one dispatch): blocks [0,3072) cast x fp32->bf16 (+ zero the
// 8 per-XCD attn counters); blocks [3072,5376) transpose-cast both weights.
// ---------------------------------------------------------------------------
__global__ __launch_bounds__(256) void prep_kernel(const float* __restrict__ x,
                                                   const float* __restrict__ Wqkv,
                                                   const float* __restrict__ Wout,
                                                   u16* __restrict__ xb,
                                                   u16* __restrict__ WqkvT,
                                                   u16* __restrict__ WoutT,
                                                   int* __restrict__ counter) {
  __shared__ u16 t[32][33];
  const int bx = blockIdx.x;
  const int tid = threadIdx.x;
  if (bx < 3072) {
    if (bx == 0 && tid < 8) counter[tid] = 0;
    const int i = (bx * 256 + tid) * 4;
    float4 v = *(const float4*)(x + i);
    ushort4 s;
    s.x = f2bf(v.x); s.y = f2bf(v.y); s.z = f2bf(v.z); s.w = f2bf(v.w);
    *(ushort4*)(xb + i) = s;
  } else {
    const int idx = bx - 3072;
    const int gx = idx % 96, gy = idx / 96;        // old grid (96, 24)
    const bool isA = gx < (N3n / 32);
    const float* in = isA ? Wqkv : Wout;
    u16* out = isA ? WqkvT : WoutT;
    const int Cc = isA ? N3n : Cn;
    const int c0 = (isA ? gx : gx - N3n / 32) * 32;
    const int r0 = gy * 32;
    const int tx = tid & 31, ty = tid >> 5;
#pragma unroll
    for (int i = 0; i < 4; i++)
      t[ty * 4 + i][tx] = f2bf(in[(size_t)(r0 + ty * 4 + i) * Cc + c0 + tx]);
    __syncthreads();
#pragma unroll
    for (int i = 0; i < 4; i++)
      out[(size_t)(c0 + ty * 4 + i) * Cn + r0 + tx] = t[tx][ty * 4 + i];
  }
}

// ---------------------------------------------------------------------------
// MFMA GEMM (unchanged from R12 — verified): 128x128 tile, BK=64, 1-barrier
// prefetch double-buffer, XOR row-swizzle via pre-swizzled DMA source.
// ---------------------------------------------------------------------------
#define BK 64
#define GT_W (128 * BK)   // one A or B tile in u16 (16 KB)

template <int EPI>
__global__ __launch_bounds__(256) void mfma_gemm(const u16* __restrict__ A,
                                                 const u16* __restrict__ BT,
                                                 u16* __restrict__ Q,
                                                 u16* __restrict__ Kd,
                                                 u16* __restrict__ VT,
                                                 float* __restrict__ out) {
  __shared__ __align__(16) u16 Ash[2 * GT_W];   // 32 KB (double-buffered)
  __shared__ __align__(16) u16 Bsh[2 * GT_W];   // 32 KB
  const int tid = threadIdx.x;
  const int wv = tid >> 6, lane = tid & 63;
  const int lo = lane & 15, quad = lane >> 4;
  const int lo7 = lo & 7;
  const int wm = wv & 1, wn = wv >> 1;

  const int nwg = gridDim.x * gridDim.y;       // 576 or 192, both % 8 == 0
  const int cpx = nwg >> 3;
  const int lid = blockIdx.y * gridDim.x + blockIdx.x;
  const int swz = (lid & 7) * cpx + (lid >> 3);
  const int n0 = (swz % gridDim.x) * 128;
  const int m0 = (swz / gridDim.x) * 128;

  const int srow = lane >> 3;                    // row within 8-row DMA chunk
  const int kcol = ((lane & 7) ^ srow) << 3;     // pre-swizzled source col

  f32x4 acc[4][4];
#pragma unroll
  for (int i = 0; i < 4; i++)
#pragma unroll
    for (int j = 0; j < 4; j++) acc[i][j] = f32x4{0.f, 0.f, 0.f, 0.f};

  auto stage = [&](int k0, int buf) {
#pragma unroll
    for (int c = 0; c < 4; c++) {
      const int rb = (wv << 5) + (c << 3);
      const int gr = rb + srow;
      __builtin_amdgcn_global_load_lds(
          (gas1_t)(A + (size_t)(m0 + gr) * Cn + k0 + kcol),
          (las3_t)(&Ash[buf * GT_W + rb * BK]), 16, 0, 0);
      __builtin_amdgcn_global_load_lds(
          (gas1_t)(BT + (size_t)(n0 + gr) * Cn + k0 + kcol),
          (las3_t)(&Bsh[buf * GT_W + rb * BK]), 16, 0, 0);
    }
  };

  stage(0, 0);
  __syncthreads();   // vmcnt(0) drain before s_barrier -> buffer 0 ready

  int cur = 0;
  for (int k0 = 0; k0 < Cn; k0 += BK) {
    if (k0 + BK < Cn) stage(k0 + BK, cur ^ 1);   // prefetch next slice

    const u16* Ab = &Ash[cur * GT_W];
    const u16* Bb = &Bsh[cur * GT_W];
    bf16x8 af[4][2], bfr[4][2];
#pragma unroll
    for (int t = 0; t < 4; t++) {
#pragma unroll
      for (int s = 0; s < 2; s++) {
        const int cc = ((s * 4 + quad) ^ lo7) << 3;   // swizzled read chunk
        af[t][s]  = *(const bf16x8*)&Ab[(wm * 64 + t * 16 + lo) * BK + cc];
        bfr[t][s] = *(const bf16x8*)&Bb[(wn * 64 + t * 16 + lo) * BK + cc];
      }
    }
#pragma unroll
    for (int mt = 0; mt < 4; mt++)
#pragma unroll
      for (int nt = 0; nt < 4; nt++) {
        acc[mt][nt] = __builtin_amdgcn_mfma_f32_16x16x32_bf16(af[mt][0], bfr[nt][0],
                                                              acc[mt][nt], 0, 0, 0);
        acc[mt][nt] = __builtin_amdgcn_mfma_f32_16x16x32_bf16(af[mt][1], bfr[nt][1],
                                                              acc[mt][nt], 0, 0, 0);
      }
    __syncthreads();   // publishes next tile (vmcnt drain) + WAR guard
    cur ^= 1;
  }

  if (EPI == 0) {
    const int which = n0 / Cn;
    const int h = ((n0 % Cn) >> 6) + wn;
    const int bb = m0 >> 11;
    const int t_base = (m0 & (Tn - 1)) + wm * 64;
    if (which < 2) {
      u16* dst = ((which == 0) ? Q : Kd) + (size_t)(bb * Hn + h) * Tn * Dn;
#pragma unroll
      for (int mt = 0; mt < 4; mt++)
#pragma unroll
        for (int nt = 0; nt < 4; nt++)
#pragma unroll
          for (int r = 0; r < 4; r++) {
            const int t = t_base + mt * 16 + (quad << 2) + r;
            dst[(size_t)t * Dn + nt * 16 + lo] = f2bf(acc[mt][nt][r]);
          }
    } else {
      u16* dst = VT + (size_t)(bb * Hn + h) * Dn * Tn;
#pragma unroll
      for (int mt = 0; mt < 4; mt++)
#pragma unroll
        for (int nt = 0; nt < 4; nt++) {
          const int t = t_base + mt * 16 + (quad << 2);
          const int d = nt * 16 + lo;
          ushort4 st;
          st.x = f2bf(acc[mt][nt][0]); st.y = f2bf(acc[mt][nt][1]);
          st.z = f2bf(acc[mt][nt][2]); st.w = f2bf(acc[mt][nt][3]);
          *(ushort4*)&dst[(size_t)d * Tn + t] = st;
        }
    }
  } else {
#pragma unroll
    for (int mt = 0; mt < 4; mt++)
#pragma unroll
      for (int nt = 0; nt < 4; nt++)
#pragma unroll
        for (int r = 0; r < 4; r++) {
          const int m = m0 + wm * 64 + mt * 16 + (quad << 2) + r;
          out[(size_t)m * Cn + n0 + wn * 64 + nt * 16 + lo] = acc[mt][nt][r];
        }
  }
}

// ---------------------------------------------------------------------------
// Causal flash attention (R19 = R12-verified + T5 setprio around the MFMA
// clusters). KVBLK=128, kv-split schedule, XCD-local stealing, K via
// global_load_lds w/ pre-swizzled source, V reg-staged permuted, in-register
// P (cvt_pk + permlane32_swap), defer-max, per-lane partial l. setprio is a
// pure scheduler hint: 2 independent blocks/CU at different phases = the
// m191 regime where it measured +4-7%.
// ---------------------------------------------------------------------------
#define KT_W (128 * 64)   // one K tile  [128][64] in u16 (16 KB)
#define VH_W (64 * 64)    // one V half  [64][64]  in u16 (8 KB)

__global__ __launch_bounds__(256) void attn_kernel(const u16* __restrict__ Q,
                                                   const u16* __restrict__ K,
                                                   const u16* __restrict__ VT,
                                                   u16* __restrict__ O,
                                                   int* __restrict__ counter,
                                                   float* __restrict__ po,
                                                   float* __restrict__ pm,
                                                   float* __restrict__ pl) {
  __shared__ __align__(16) u16 Ksh[2 * KT_W];   // [buf][128][64]
  __shared__ __align__(16) u16 Vsh[4 * VH_W];   // [buf][half][64][64]
  int* sip = (int*)&Ksh[KT_W];                  // aliased item broadcast

  const int tid = threadIdx.x;
  const int g = blockIdx.x & 7;           // XCD group (locality hint)
  const int wv = tid >> 6, lane = tid & 63;
  const int lo = lane & 15, quad = lane >> 4;
  const int lo7 = lo & 7;
  const int ck0 = (quad ^ lo7) << 3;      // swizzled col block for slot quad
  const int ck1 = ck0 ^ 32;               // swizzled col block for slot quad+4
  const int sr = tid >> 3;                // V staging row 0..31
  const int sc = (tid & 7) << 3;          // V global col (u16) 0..56
  const int kcol = ((lane & 7) ^ (lane >> 3)) << 3;   // K DMA src pre-swizzle
  const int t7 = tid & 7;
  const int vb0 = (((t7 & 6) ^ (sr & 7)) << 3) + ((t7 & 1) << 2);
  const int vb1 = ((((t7 & 6) | 1) ^ (sr & 7)) << 3) + ((t7 & 1) << 2);

  for (;;) {
    if (tid == 0) *sip = atomicAdd(&counter[g], 1);
    __syncthreads();                  // broadcast item; fences LDS reuse
    const int il = *sip;
    if (il >= NIT_G) return;          // uniform exit

    const unsigned int e = SCHED[il / 3];
    const int qt = e >> 24, ck = e & 255;
    const int jstart = ((e >> 16) & 255) << 7;   // 128-kv units
    const int jend   = ((e >> 8) & 255) << 7;
    const int q0 = qt << 6;
    const int hb = g * 3 + il % 3;    // this group's local head
    const int h = hb % 12, b = hb / 12;
    const size_t base = (size_t)(b * Hn + h) * Tn * Dn;   // Q/K [.,T,64]
    const size_t vtb  = (size_t)(b * Hn + h) * Dn * Tn;   // VT  [.,64,T]
    const u16* Kg = K + base;

    const u16* qp = Q + base + (size_t)(q0 + (wv << 4) + lo) * Dn + (quad << 3);
    const bf16x8 aq0 = *(const bf16x8*)qp;
    const bf16x8 aq1 = *(const bf16x8*)(qp + 32);

    f32x4 o[4] = {f32x4{0,0,0,0}, f32x4{0,0,0,0}, f32x4{0,0,0,0}, f32x4{0,0,0,0}};
    float m1 = MASKVAL;               // running max (UNSCALED score domain)
    float l1 = 0.f;                   // per-lane partial denom

    // prologue: stage first 128-kv tile into buffer 0
#pragma unroll
    for (int c = 0; c < 4; c++) {
      const int rb = (wv << 5) + (c << 3);
      __builtin_amdgcn_global_load_lds(
          (gas1_t)(Kg + (size_t)(jstart + rb + (lane >> 3)) * Dn + kcol),
          (las3_t)(&Ksh[rb * 64]), 16, 0, 0);
    }
#pragma unroll
    for (int hf = 0; hf < 2; hf++)
#pragma unroll
      for (int it = 0; it < 2; it++) {
        const int r = sr + it * 32;
        union { ushort8_t u; uint2v hh[2]; } vv;
        vv.u = *(const ushort8_t*)(VT + vtb + (size_t)r * Tn + jstart + hf * 64 + sc);
        *(uint2v*)&Vsh[hf * VH_W + r * 64 + vb0] = vv.hh[0];
        *(uint2v*)&Vsh[hf * VH_W + r * 64 + vb1] = vv.hh[1];
      }
    __syncthreads();

    int cur = 0;
    const int qg = q0 + (wv << 4) + lo;   // this lane's GLOBAL q row

    for (int j0 = jstart; j0 < jend; j0 += 128) {
      const bool hasnext = (j0 + 128 < jend);

      // next-tile staging issue: K DMA into inactive buffer; V to regs (T14)
      ushort8_t vr[4];
      if (hasnext) {
        const int nb = cur ^ 1;
#pragma unroll
        for (int c = 0; c < 4; c++) {
          const int rb = (wv << 5) + (c << 3);
          __builtin_amdgcn_global_load_lds(
              (gas1_t)(Kg + (size_t)(j0 + 128 + rb + (lane >> 3)) * Dn + kcol),
              (las3_t)(&Ksh[nb * KT_W + rb * 64]), 16, 0, 0);
        }
#pragma unroll
        for (int hf = 0; hf < 2; hf++)
#pragma unroll
          for (int it = 0; it < 2; it++) {
            const int r = sr + it * 32;
            vr[hf * 2 + it] =
                *(const ushort8_t*)(VT + vtb + (size_t)r * Tn + j0 + 128 + hf * 64 + sc);
          }
      }

      const u16* Kb_ = &Ksh[cur * KT_W];
      const u16* VbA = &Vsh[cur * 2 * VH_W];
      const u16* VbB = VbA + VH_W;

      // QK^T swapped, 8 kv subtiles: s[nt][r] = S[q=qg][kv = j0+nt*16+quad*4+r]
      f32x4 s[8];
      __builtin_amdgcn_s_setprio(1);
#pragma unroll
      for (int nt = 0; nt < 8; nt++) {
        const bf16x8 bk0 = *(const bf16x8*)(&Kb_[(nt * 16 + lo) * 64 + ck0]);
        const bf16x8 bk1 = *(const bf16x8*)(&Kb_[(nt * 16 + lo) * 64 + ck1]);
        f32x4 a = {0.f, 0.f, 0.f, 0.f};
        a = __builtin_amdgcn_mfma_f32_16x16x32_bf16(bk0, aq0, a, 0, 0, 0);
        a = __builtin_amdgcn_mfma_f32_16x16x32_bf16(bk1, aq1, a, 0, 0, 0);
        s[nt] = a;
      }
      __builtin_amdgcn_s_setprio(0);

      // causal mask: only the last step of a tile can cross the diagonal
      if (j0 + 128 > q0) {
#pragma unroll
        for (int nt = 0; nt < 8; nt++)
#pragma unroll
          for (int r = 0; r < 4; r++) {
            const int kvg = j0 + nt * 16 + (quad << 2) + r;
            if (kvg > qg) s[nt][r] = MASKVAL;
          }
      }

      // local max over this lane's 32 kv values — tree
      float gm[8];
#pragma unroll
      for (int nt = 0; nt < 8; nt++)
        gm[nt] = fmaxf(fmaxf(s[nt][0], s[nt][1]), fmaxf(s[nt][2], s[nt][3]));
      const float pmax = fmaxf(fmaxf(fmaxf(gm[0], gm[1]), fmaxf(gm[2], gm[3])),
                               fmaxf(fmaxf(gm[4], gm[5]), fmaxf(gm[6], gm[7])));

      // defer-max: only pay the reduce+rescale when the gap grows too large
      if (!__all(pmax <= m1 + DEFER_THR)) {
        float mr = fmaxf(pmax, __shfl_xor(pmax, 16));
        mr = fmaxf(mr, __shfl_xor(mr, 32));
        const float mnew = fmaxf(m1, mr);
        const float alpha = __builtin_amdgcn_exp2f(L2E8 * (m1 - mnew));
        m1 = mnew;
        l1 *= alpha;
        float ar[4];
#pragma unroll
        for (int r = 0; r < 4; r++) ar[r] = __shfl(alpha, (quad << 2) + r);
#pragma unroll
        for (int nt = 0; nt < 4; nt++)
#pragma unroll
          for (int r = 0; r < 4; r++) o[nt][r] *= ar[r];
      }

      // exp2 with folded 0.125*log2e; masked entries underflow to 0
      const float mb2 = L2E8 * m1;
#pragma unroll
      for (int nt = 0; nt < 8; nt++)
#pragma unroll
        for (int r = 0; r < 4; r++)
          s[nt][r] = __builtin_amdgcn_exp2f(L2E8 * s[nt][r] - mb2);
      {
        float gs[8];
#pragma unroll
        for (int nt = 0; nt < 8; nt++)
          gs[nt] = (s[nt][0] + s[nt][1]) + (s[nt][2] + s[nt][3]);
        l1 += ((gs[0] + gs[1]) + (gs[2] + gs[3])) +
              ((gs[4] + gs[5]) + (gs[6] + gs[7]));
      }

      // T12 per 64-half: P -> A-fragments in-register (cvt_pk + permlane32_swap)
      unsigned int A0, B0, A1, B1, A2, B2, A3, B3;
      union { unsigned int w[4]; bf16x8 v; } pa0u, pa1u, pa2u, pa3u;
      // half A: s[0..3]
      asm("v_cvt_pk_bf16_f32 %0, %1, %2" : "=v"(A0) : "v"(s[0][0]), "v"(s[0][1]));
      asm("v_cvt_pk_bf16_f32 %0, %1, %2" : "=v"(B0) : "v"(s[0][2]), "v"(s[0][3]));
      asm("v_cvt_pk_bf16_f32 %0, %1, %2" : "=v"(A1) : "v"(s[1][0]), "v"(s[1][1]));
      asm("v_cvt_pk_bf16_f32 %0, %1, %2" : "=v"(B1) : "v"(s[1][2]), "v"(s[1][3]));
      asm("v_cvt_pk_bf16_f32 %0, %1, %2" : "=v"(A2) : "v"(s[2][0]), "v"(s[2][1]));
      asm("v_cvt_pk_bf16_f32 %0, %1, %2" : "=v"(B2) : "v"(s[2][2]), "v"(s[2][3]));
      asm("v_cvt_pk_bf16_f32 %0, %1, %2" : "=v"(A3) : "v"(s[3][0]), "v"(s[3][1]));
      asm("v_cvt_pk_bf16_f32 %0, %1, %2" : "=v"(B3) : "v"(s[3][2]), "v"(s[3][3]));
      {
        const auto rA01 = __builtin_amdgcn_permlane32_swap(A0, A1, false, false);
        const auto rB01 = __builtin_amdgcn_permlane32_swap(B0, B1, false, false);
        const auto rA23 = __builtin_amdgcn_permlane32_swap(A2, A3, false, false);
        const auto rB23 = __builtin_amdgcn_permlane32_swap(B2, B3, false, false);
        pa0u.w[0] = rA01[0]; pa0u.w[1] = rB01[0];
        pa0u.w[2] = rA01[1]; pa0u.w[3] = rB01[1];
        pa1u.w[0] = rA23[0]; pa1u.w[1] = rB23[0];
        pa1u.w[2] = rA23[1]; pa1u.w[3] = rB23[1];
      }
      // half B: s[4..7]
      asm("v_cvt_pk_bf16_f32 %0, %1, %2" : "=v"(A0) : "v"(s[4][0]), "v"(s[4][1]));
      asm("v_cvt_pk_bf16_f32 %0, %1, %2" : "=v"(B0) : "v"(s[4][2]), "v"(s[4][3]));
      asm("v_cvt_pk_bf16_f32 %0, %1, %2" : "=v"(A1) : "v"(s[5][0]), "v"(s[5][1]));
      asm("v_cvt_pk_bf16_f32 %0, %1, %2" : "=v"(B1) : "v"(s[5][2]), "v"(s[5][3]));
      asm("v_cvt_pk_bf16_f32 %0, %1, %2" : "=v"(A2) : "v"(s[6][0]), "v"(s[6][1]));
      asm("v_cvt_pk_bf16_f32 %0, %1, %2" : "=v"(B2) : "v"(s[6][2]), "v"(s[6][3]));
      asm("v_cvt_pk_bf16_f32 %0, %1, %2" : "=v"(A3) : "v"(s[7][0]), "v"(s[7][1]));
      asm("v_cvt_pk_bf16_f32 %0, %1, %2" : "=v"(B3) : "v"(s[7][2]), "v"(s[7][3]));
      {
        const auto rA01 = __builtin_amdgcn_permlane32_swap(A0, A1, false, false);
        const auto rB01 = __builtin_amdgcn_permlane32_swap(B0, B1, false, false);
        const auto rA23 = __builtin_amdgcn_permlane32_swap(A2, A3, false, false);
        const auto rB23 = __builtin_amdgcn_permlane32_swap(B2, B3, false, false);
        pa2u.w[0] = rA01[0]; pa2u.w[1] = rB01[0];
        pa2u.w[2] = rA01[1]; pa2u.w[3] = rB01[1];
        pa3u.w[0] = rA23[0]; pa3u.w[1] = rB23[0];
        pa3u.w[2] = rA23[1]; pa3u.w[3] = rB23[1];
      }

      __builtin_amdgcn_s_setprio(1);
#pragma unroll
      for (int nt = 0; nt < 4; nt++) {
        const bf16x8 bvA0 = *(const bf16x8*)(&VbA[(nt * 16 + lo) * 64 + ck0]);
        const bf16x8 bvA1 = *(const bf16x8*)(&VbA[(nt * 16 + lo) * 64 + ck1]);
        const bf16x8 bvB0 = *(const bf16x8*)(&VbB[(nt * 16 + lo) * 64 + ck0]);
        const bf16x8 bvB1 = *(const bf16x8*)(&VbB[(nt * 16 + lo) * 64 + ck1]);
        o[nt] = __builtin_amdgcn_mfma_f32_16x16x32_bf16(pa0u.v, bvA0, o[nt], 0, 0, 0);
        o[nt] = __builtin_amdgcn_mfma_f32_16x16x32_bf16(pa1u.v, bvA1, o[nt], 0, 0, 0);
        o[nt] = __builtin_amdgcn_mfma_f32_16x16x32_bf16(pa2u.v, bvB0, o[nt], 0, 0, 0);
        o[nt] = __builtin_amdgcn_mfma_f32_16x16x32_bf16(pa3u.v, bvB1, o[nt], 0, 0, 0);
      }
      __builtin_amdgcn_s_setprio(0);

      // write prefetched V into the other buffer, then the SINGLE barrier
      if (hasnext) {
        const int nb = cur ^ 1;
#pragma unroll
        for (int hf = 0; hf < 2; hf++)
#pragma unroll
          for (int it = 0; it < 2; it++) {
            const int r = sr + it * 32;
            union { ushort8_t u; uint2v hh[2]; } vv;
            vv.u = vr[hf * 2 + it];
            *(uint2v*)&Vsh[nb * 2 * VH_W + hf * VH_W + r * 64 + vb0] = vv.hh[0];
            *(uint2v*)&Vsh[nb * 2 * VH_W + hf * VH_W + r * 64 + vb1] = vv.hh[1];
          }
      }
      __syncthreads();
      cur ^= 1;
    }

    // epilogue: reduce per-lane partial l across the 4 quads, then transpose
    float lt = l1;
    lt += __shfl_xor(lt, 16);
    lt += __shfl_xor(lt, 32);
    const float linv = 1.f / lt;
    float ir[4];
#pragma unroll
    for (int r = 0; r < 4; r++) ir[r] = __shfl(linv, (quad << 2) + r);

    if (ck == 2) {
      // unsplit: write O directly
#pragma unroll
      for (int nt = 0; nt < 4; nt++)
#pragma unroll
        for (int r = 0; r < 4; r++) {
          const int row = q0 + (wv << 4) + (quad << 2) + r;
          const int col = h * 64 + nt * 16 + lo;
          O[(size_t)(b * Tn + row) * Cn + col] = f2bf(o[nt][r] * ir[r]);
        }
    } else {
      // split chunk: write normalized f32 partial + (m,l); combine kernel
      // (stream-ordered, next dispatch) merges the two chunks.
      const int st = hb * 16 + (qt - 16);          // split-tile index [0,384)
      const int pidx = st * 2 + ck;
      float* pO = po + ((size_t)pidx << 12);
#pragma unroll
      for (int nt = 0; nt < 4; nt++)
#pragma unroll
        for (int r = 0; r < 4; r++)
          pO[((wv << 4) + (quad << 2) + r) * 64 + nt * 16 + lo] = o[nt][r] * ir[r];
      if (quad == 0) {
        pm[pidx * 64 + (wv << 4) + lo] = m1;   // m1/lt are quad-uniform
        pl[pidx * 64 + (wv << 4) + lo] = lt;
      }
    }
  }
}

// ---------------------------------------------------------------------------
// Combine kernel: one block per split tile. Merges the two normalized chunk
// partials with standard flash weights and writes bf16 O. Stream order
// guarantees visibility — no flags/fences needed.
// ---------------------------------------------------------------------------
__global__ __launch_bounds__(256) void combine_kernel(const float* __restrict__ po,
                                                      const float* __restrict__ pm,
                                                      const float* __restrict__ pl,
                                                      u16* __restrict__ O) {
  const int st = blockIdx.x;           // [0,384): st = hb*16 + (qt-16)
  const int hb = st >> 4;
  const int h = hb % 12, b = hb / 12;
  const int q0 = (16 + (st & 15)) << 6;
  const int tid = threadIdx.x;
  const int row = tid >> 2, cc0 = (tid & 3) << 4;
  const float* pa = po + (((size_t)st * 2) << 12) + row * 64 + cc0;
  const float* pb = pa + 4096;
  const float ma = pm[st * 128 + row],      la = pl[st * 128 + row];
  const float mb = pm[st * 128 + 64 + row], lb = pl[st * 128 + 64 + row];
  const float mm = fmaxf(ma, mb);
  float wa = la * __builtin_amdgcn_exp2f(L2E8 * (ma - mm));
  float wb = lb * __builtin_amdgcn_exp2f(L2E8 * (mb - mm));
  const float wi = 1.f / (wa + wb);
  wa *= wi; wb *= wi;
  u16* Orow = O + (size_t)(b * Tn + q0 + row) * Cn + h * 64 + cc0;
#pragma unroll
  for (int i = 0; i < 16; i += 4) {
    const float4 va = *(const float4*)(pa + i);
    const float4 vb = *(const float4*)(pb + i);
    ushort4 s4;
    s4.x = f2bf(wa * va.x + wb * vb.x);
    s4.y = f2bf(wa * va.y + wb * vb.y);
    s4.z = f2bf(wa * va.z + wb * vb.z);
    s4.w = f2bf(wa * va.w + wb * vb.w);
    *(ushort4*)(Orow + i) = s4;
  }
}

// ---------------------------------------------------------------------------
extern "C" void kernel_launch(void* const* d_in, const int* in_sizes, int n_in,
                              void* d_out, int out_size, void* d_ws, size_t ws_size,
                              hipStream_t stream) {
  const float* x    = (const float*)d_in[0];   // [B,T,C] fp32
  const float* Wqkv = (const float*)d_in[1];   // [C,3C] fp32
  const float* Wout = (const float*)d_in[2];   // [C,C] fp32
  float* out = (float*)d_out;                  // [B,T,C] fp32

  const size_t per = (size_t)Bn * Hn * Tn * Dn;     // 3,145,728 elems
  u16* xb    = (u16*)d_ws;                          // [4096,768] bf16
  u16* WqkvT = xb + (size_t)Mn * Cn;                // [2304,768] bf16
  u16* WoutT = WqkvT + (size_t)N3n * Cn;            // [768,768]  bf16
  u16* Qb    = WoutT + (size_t)Cn * Cn;             // [B,H,T,DH] bf16
  u16* Kb    = Qb + per;                            // [B,H,T,DH] bf16
  u16* VTb   = Kb + per;                            // [B,H,DH,T] bf16
  u16* attn  = VTb + per;                           // [B,T,C]    bf16
  int* counter = (int*)(attn + (size_t)Mn * Cn);    // [512] ints (8 used)
  float* po = (float*)(counter + 512);              // [768][64][64] f32 partials
  float* pm = po + (size_t)768 * 4096;              // [768][64] f32
  float* pl = pm + (size_t)768 * 64;                // [768][64] f32
  // total ws use: ~49.2 MB (< 50.3 MB available)

  prep_kernel<<<dim3(3072 + 2304), 256, 0, stream>>>(x, Wqkv, Wout, xb, WqkvT,
                                                     WoutT, counter);
  mfma_gemm<0><<<dim3(N3n / 128, Mn / 128), 256, 0, stream>>>(xb, WqkvT, Qb, Kb, VTb, nullptr);
  attn_kernel<<<dim3(512), 256, 0, stream>>>(Qb, Kb, VTb, attn, counter, po, pm, pl);
  combine_kernel<<<dim3(384), 256, 0, stream>>>(po, pm, pl, attn);
  mfma_gemm<1><<<dim3(Cn / 128, Mn / 128), 256, 0, stream>>>(attn, WoutT, nullptr, nullptr, nullptr, out);
}

// Round 15
// 158.331 us; speedup vs baseline: 1.0506x; 1.0506x over previous
//
#include <hip/hip_runtime.h>
#include <hip/hip_bf16.h>

// Problem constants (B,T,C,H,DH) = (2,2048,768,12,64)
#define Bn 2
#define Tn 2048
#define Cn 768
#define Hn 12
#define Dn 64
#define N3n 2304
#define Mn 4096   // B*T

#define MASKVAL (-30000.f)   // finite sentinel; scores are O(+-40) unscaled
#define NIT_G 96             // items per XCD group: 32 q-tiles * 3 (h,b)
#define DEFER_THR 64.f       // unscaled-score gap; P bounded by e^8
#define L2E8 0.1803368801111204f   // 0.125 * log2(e): exp(0.125*x) = exp2(L2E8*x)

typedef unsigned short u16;
typedef __attribute__((ext_vector_type(8))) unsigned short ushort8_t;
typedef __attribute__((ext_vector_type(8))) short bf16x8;   // 8 bf16 in 4 VGPRs
typedef __attribute__((ext_vector_type(4))) float f32x4;
typedef __attribute__((ext_vector_type(2))) unsigned int uint2v;  // 8B aligned
typedef __attribute__((address_space(1))) unsigned int* gas1_t;   // global
typedef __attribute__((address_space(3))) unsigned int* las3_t;   // LDS

__device__ __forceinline__ float bf2f(u16 u) {
  union { unsigned int i; float f; } v; v.i = ((unsigned int)u) << 16; return v.f;
}
__device__ __forceinline__ u16 f2bf(float f) {
  union { float f; unsigned int i; } v; v.f = f;
  return (u16)((v.i + 0x7fffu + ((v.i >> 16) & 1u)) >> 16);
}

// ---------------------------------------------------------------------------
// Schedule (R20): kv-split REMOVED — throughput-bound regime makes the split
// net-negative (combine dispatch + gap + partial traffic + 384 extra
// prologues > the ~3 steps of makespan it saved). 32 unsplit entries, LPT
// order (longest first). entry = (qt<<8) | L ; L = ceil((qt+1)/2) 128-kv
// steps. All items write O directly.
// ---------------------------------------------------------------------------
#define E(qt, L) (((qt) << 8) | (L))
__constant__ unsigned int SCHED[32] = {
    E(31, 16), E(30, 16), E(29, 15), E(28, 15), E(27, 14), E(26, 14),
    E(25, 13), E(24, 13), E(23, 12), E(22, 12), E(21, 11), E(20, 11),
    E(19, 10), E(18, 10), E(17, 9),  E(16, 9),  E(15, 8),  E(14, 8),
    E(13, 7),  E(12, 7),  E(11, 6),  E(10, 6),  E(9, 5),   E(8, 5),
    E(7, 4),   E(6, 4),   E(5, 3),   E(4, 3),   E(3, 2),   E(2, 2),
    E(1, 1),   E(0, 1)};

// ---------------------------------------------------------------------------
// Prep (merged, one dispatch): blocks [0,3072) cast x fp32->bf16 (+ zero the
// 8 per-XCD attn counters); blocks [3072,5376) transpose-cast both weights.
// ---------------------------------------------------------------------------
__global__ __launch_bounds__(256) void prep_kernel(const float* __restrict__ x,
                                                   const float* __restrict__ Wqkv,
                                                   const float* __restrict__ Wout,
                                                   u16* __restrict__ xb,
                                                   u16* __restrict__ WqkvT,
                                                   u16* __restrict__ WoutT,
                                                   int* __restrict__ counter) {
  __shared__ u16 t[32][33];
  const int bx = blockIdx.x;
  const int tid = threadIdx.x;
  if (bx < 3072) {
    if (bx == 0 && tid < 8) counter[tid] = 0;
    const int i = (bx * 256 + tid) * 4;
    float4 v = *(const float4*)(x + i);
    ushort4 s;
    s.x = f2bf(v.x); s.y = f2bf(v.y); s.z = f2bf(v.z); s.w = f2bf(v.w);
    *(ushort4*)(xb + i) = s;
  } else {
    const int idx = bx - 3072;
    const int gx = idx % 96, gy = idx / 96;        // old grid (96, 24)
    const bool isA = gx < (N3n / 32);
    const float* in = isA ? Wqkv : Wout;
    u16* out = isA ? WqkvT : WoutT;
    const int Cc = isA ? N3n : Cn;
    const int c0 = (isA ? gx : gx - N3n / 32) * 32;
    const int r0 = gy * 32;
    const int tx = tid & 31, ty = tid >> 5;
#pragma unroll
    for (int i = 0; i < 4; i++)
      t[ty * 4 + i][tx] = f2bf(in[(size_t)(r0 + ty * 4 + i) * Cc + c0 + tx]);
    __syncthreads();
#pragma unroll
    for (int i = 0; i < 4; i++)
      out[(size_t)(c0 + ty * 4 + i) * Cn + r0 + tx] = t[tx][ty * 4 + i];
  }
}

// ---------------------------------------------------------------------------
// MFMA GEMM (unchanged from R12 — verified): 128x128 tile, BK=64, 1-barrier
// prefetch double-buffer, XOR row-swizzle via pre-swizzled DMA source.
// ---------------------------------------------------------------------------
#define BK 64
#define GT_W (128 * BK)   // one A or B tile in u16 (16 KB)

template <int EPI>
__global__ __launch_bounds__(256) void mfma_gemm(const u16* __restrict__ A,
                                                 const u16* __restrict__ BT,
                                                 u16* __restrict__ Q,
                                                 u16* __restrict__ Kd,
                                                 u16* __restrict__ VT,
                                                 float* __restrict__ out) {
  __shared__ __align__(16) u16 Ash[2 * GT_W];   // 32 KB (double-buffered)
  __shared__ __align__(16) u16 Bsh[2 * GT_W];   // 32 KB
  const int tid = threadIdx.x;
  const int wv = tid >> 6, lane = tid & 63;
  const int lo = lane & 15, quad = lane >> 4;
  const int lo7 = lo & 7;
  const int wm = wv & 1, wn = wv >> 1;

  const int nwg = gridDim.x * gridDim.y;       // 576 or 192, both % 8 == 0
  const int cpx = nwg >> 3;
  const int lid = blockIdx.y * gridDim.x + blockIdx.x;
  const int swz = (lid & 7) * cpx + (lid >> 3);
  const int n0 = (swz % gridDim.x) * 128;
  const int m0 = (swz / gridDim.x) * 128;

  const int srow = lane >> 3;                    // row within 8-row DMA chunk
  const int kcol = ((lane & 7) ^ srow) << 3;     // pre-swizzled source col

  f32x4 acc[4][4];
#pragma unroll
  for (int i = 0; i < 4; i++)
#pragma unroll
    for (int j = 0; j < 4; j++) acc[i][j] = f32x4{0.f, 0.f, 0.f, 0.f};

  auto stage = [&](int k0, int buf) {
#pragma unroll
    for (int c = 0; c < 4; c++) {
      const int rb = (wv << 5) + (c << 3);
      const int gr = rb + srow;
      __builtin_amdgcn_global_load_lds(
          (gas1_t)(A + (size_t)(m0 + gr) * Cn + k0 + kcol),
          (las3_t)(&Ash[buf * GT_W + rb * BK]), 16, 0, 0);
      __builtin_amdgcn_global_load_lds(
          (gas1_t)(BT + (size_t)(n0 + gr) * Cn + k0 + kcol),
          (las3_t)(&Bsh[buf * GT_W + rb * BK]), 16, 0, 0);
    }
  };

  stage(0, 0);
  __syncthreads();   // vmcnt(0) drain before s_barrier -> buffer 0 ready

  int cur = 0;
  for (int k0 = 0; k0 < Cn; k0 += BK) {
    if (k0 + BK < Cn) stage(k0 + BK, cur ^ 1);   // prefetch next slice

    const u16* Ab = &Ash[cur * GT_W];
    const u16* Bb = &Bsh[cur * GT_W];
    bf16x8 af[4][2], bfr[4][2];
#pragma unroll
    for (int t = 0; t < 4; t++) {
#pragma unroll
      for (int s = 0; s < 2; s++) {
        const int cc = ((s * 4 + quad) ^ lo7) << 3;   // swizzled read chunk
        af[t][s]  = *(const bf16x8*)&Ab[(wm * 64 + t * 16 + lo) * BK + cc];
        bfr[t][s] = *(const bf16x8*)&Bb[(wn * 64 + t * 16 + lo) * BK + cc];
      }
    }
#pragma unroll
    for (int mt = 0; mt < 4; mt++)
#pragma unroll
      for (int nt = 0; nt < 4; nt++) {
        acc[mt][nt] = __builtin_amdgcn_mfma_f32_16x16x32_bf16(af[mt][0], bfr[nt][0],
                                                              acc[mt][nt], 0, 0, 0);
        acc[mt][nt] = __builtin_amdgcn_mfma_f32_16x16x32_bf16(af[mt][1], bfr[nt][1],
                                                              acc[mt][nt], 0, 0, 0);
      }
    __syncthreads();   // publishes next tile (vmcnt drain) + WAR guard
    cur ^= 1;
  }

  if (EPI == 0) {
    const int which = n0 / Cn;
    const int h = ((n0 % Cn) >> 6) + wn;
    const int bb = m0 >> 11;
    const int t_base = (m0 & (Tn - 1)) + wm * 64;
    if (which < 2) {
      u16* dst = ((which == 0) ? Q : Kd) + (size_t)(bb * Hn + h) * Tn * Dn;
#pragma unroll
      for (int mt = 0; mt < 4; mt++)
#pragma unroll
        for (int nt = 0; nt < 4; nt++)
#pragma unroll
          for (int r = 0; r < 4; r++) {
            const int t = t_base + mt * 16 + (quad << 2) + r;
            dst[(size_t)t * Dn + nt * 16 + lo] = f2bf(acc[mt][nt][r]);
          }
    } else {
      u16* dst = VT + (size_t)(bb * Hn + h) * Dn * Tn;
#pragma unroll
      for (int mt = 0; mt < 4; mt++)
#pragma unroll
        for (int nt = 0; nt < 4; nt++) {
          const int t = t_base + mt * 16 + (quad << 2);
          const int d = nt * 16 + lo;
          ushort4 st;
          st.x = f2bf(acc[mt][nt][0]); st.y = f2bf(acc[mt][nt][1]);
          st.z = f2bf(acc[mt][nt][2]); st.w = f2bf(acc[mt][nt][3]);
          *(ushort4*)&dst[(size_t)d * Tn + t] = st;
        }
    }
  } else {
#pragma unroll
    for (int mt = 0; mt < 4; mt++)
#pragma unroll
      for (int nt = 0; nt < 4; nt++)
#pragma unroll
        for (int r = 0; r < 4; r++) {
          const int m = m0 + wm * 64 + mt * 16 + (quad << 2) + r;
          out[(size_t)m * Cn + n0 + wn * 64 + nt * 16 + lo] = acc[mt][nt][r];
        }
  }
}

// ---------------------------------------------------------------------------
// Causal flash attention (R20): R14 inner loop byte-identical (KVBLK=128,
// XCD-local stealing, K via global_load_lds w/ pre-swizzled source, V
// reg-staged permuted, in-register P via cvt_pk+permlane32_swap, defer-max,
// per-lane partial l, setprio kept). kv-split removed: every item covers its
// full kv range [0, L*128) and writes O directly. No partials, no combine.
// ---------------------------------------------------------------------------
#define KT_W (128 * 64)   // one K tile  [128][64] in u16 (16 KB)
#define VH_W (64 * 64)    // one V half  [64][64]  in u16 (8 KB)

__global__ __launch_bounds__(256) void attn_kernel(const u16* __restrict__ Q,
                                                   const u16* __restrict__ K,
                                                   const u16* __restrict__ VT,
                                                   u16* __restrict__ O,
                                                   int* __restrict__ counter) {
  __shared__ __align__(16) u16 Ksh[2 * KT_W];   // [buf][128][64]
  __shared__ __align__(16) u16 Vsh[4 * VH_W];   // [buf][half][64][64]
  int* sip = (int*)&Ksh[KT_W];                  // aliased item broadcast

  const int tid = threadIdx.x;
  const int g = blockIdx.x & 7;           // XCD group (locality hint)
  const int wv = tid >> 6, lane = tid & 63;
  const int lo = lane & 15, quad = lane >> 4;
  const int lo7 = lo & 7;
  const int ck0 = (quad ^ lo7) << 3;      // swizzled col block for slot quad
  const int ck1 = ck0 ^ 32;               // swizzled col block for slot quad+4
  const int sr = tid >> 3;                // V staging row 0..31
  const int sc = (tid & 7) << 3;          // V global col (u16) 0..56
  const int kcol = ((lane & 7) ^ (lane >> 3)) << 3;   // K DMA src pre-swizzle
  const int t7 = tid & 7;
  const int vb0 = (((t7 & 6) ^ (sr & 7)) << 3) + ((t7 & 1) << 2);
  const int vb1 = ((((t7 & 6) | 1) ^ (sr & 7)) << 3) + ((t7 & 1) << 2);

  for (;;) {
    if (tid == 0) *sip = atomicAdd(&counter[g], 1);
    __syncthreads();                  // broadcast item; fences LDS reuse
    const int il = *sip;
    if (il >= NIT_G) return;          // uniform exit

    const unsigned int e = SCHED[il / 3];
    const int qt = e >> 8;
    const int jend = (e & 255) << 7;  // L * 128 kv
    const int q0 = qt << 6;
    const int hb = g * 3 + il % 3;    // this group's local head
    const int h = hb % 12, b = hb / 12;
    const size_t base = (size_t)(b * Hn + h) * Tn * Dn;   // Q/K [.,T,64]
    const size_t vtb  = (size_t)(b * Hn + h) * Dn * Tn;   // VT  [.,64,T]
    const u16* Kg = K + base;

    const u16* qp = Q + base + (size_t)(q0 + (wv << 4) + lo) * Dn + (quad << 3);
    const bf16x8 aq0 = *(const bf16x8*)qp;
    const bf16x8 aq1 = *(const bf16x8*)(qp + 32);

    f32x4 o[4] = {f32x4{0,0,0,0}, f32x4{0,0,0,0}, f32x4{0,0,0,0}, f32x4{0,0,0,0}};
    float m1 = MASKVAL;               // running max (UNSCALED score domain)
    float l1 = 0.f;                   // per-lane partial denom

    // prologue: stage first 128-kv tile into buffer 0
#pragma unroll
    for (int c = 0; c < 4; c++) {
      const int rb = (wv << 5) + (c << 3);
      __builtin_amdgcn_global_load_lds(
          (gas1_t)(Kg + (size_t)(rb + (lane >> 3)) * Dn + kcol),
          (las3_t)(&Ksh[rb * 64]), 16, 0, 0);
    }
#pragma unroll
    for (int hf = 0; hf < 2; hf++)
#pragma unroll
      for (int it = 0; it < 2; it++) {
        const int r = sr + it * 32;
        union { ushort8_t u; uint2v hh[2]; } vv;
        vv.u = *(const ushort8_t*)(VT + vtb + (size_t)r * Tn + hf * 64 + sc);
        *(uint2v*)&Vsh[hf * VH_W + r * 64 + vb0] = vv.hh[0];
        *(uint2v*)&Vsh[hf * VH_W + r * 64 + vb1] = vv.hh[1];
      }
    __syncthreads();

    int cur = 0;
    const int qg = q0 + (wv << 4) + lo;   // this lane's GLOBAL q row

    for (int j0 = 0; j0 < jend; j0 += 128) {
      const bool hasnext = (j0 + 128 < jend);

      // next-tile staging issue: K DMA into inactive buffer; V to regs (T14)
      ushort8_t vr[4];
      if (hasnext) {
        const int nb = cur ^ 1;
#pragma unroll
        for (int c = 0; c < 4; c++) {
          const int rb = (wv << 5) + (c << 3);
          __builtin_amdgcn_global_load_lds(
              (gas1_t)(Kg + (size_t)(j0 + 128 + rb + (lane >> 3)) * Dn + kcol),
              (las3_t)(&Ksh[nb * KT_W + rb * 64]), 16, 0, 0);
        }
#pragma unroll
        for (int hf = 0; hf < 2; hf++)
#pragma unroll
          for (int it = 0; it < 2; it++) {
            const int r = sr + it * 32;
            vr[hf * 2 + it] =
                *(const ushort8_t*)(VT + vtb + (size_t)r * Tn + j0 + 128 + hf * 64 + sc);
          }
      }

      const u16* Kb_ = &Ksh[cur * KT_W];
      const u16* VbA = &Vsh[cur * 2 * VH_W];
      const u16* VbB = VbA + VH_W;

      // QK^T swapped, 8 kv subtiles: s[nt][r] = S[q=qg][kv = j0+nt*16+quad*4+r]
      f32x4 s[8];
      __builtin_amdgcn_s_setprio(1);
#pragma unroll
      for (int nt = 0; nt < 8; nt++) {
        const bf16x8 bk0 = *(const bf16x8*)(&Kb_[(nt * 16 + lo) * 64 + ck0]);
        const bf16x8 bk1 = *(const bf16x8*)(&Kb_[(nt * 16 + lo) * 64 + ck1]);
        f32x4 a = {0.f, 0.f, 0.f, 0.f};
        a = __builtin_amdgcn_mfma_f32_16x16x32_bf16(bk0, aq0, a, 0, 0, 0);
        a = __builtin_amdgcn_mfma_f32_16x16x32_bf16(bk1, aq1, a, 0, 0, 0);
        s[nt] = a;
      }
      __builtin_amdgcn_s_setprio(0);

      // causal mask: only tiles crossing the diagonal need it (incl. the
      // over-read tail rows of the last tile — kvg > qg kills them)
      if (j0 + 128 > q0) {
#pragma unroll
        for (int nt = 0; nt < 8; nt++)
#pragma unroll
          for (int r = 0; r < 4; r++) {
            const int kvg = j0 + nt * 16 + (quad << 2) + r;
            if (kvg > qg) s[nt][r] = MASKVAL;
          }
      }

      // local max over this lane's 32 kv values — tree
      float gm[8];
#pragma unroll
      for (int nt = 0; nt < 8; nt++)
        gm[nt] = fmaxf(fmaxf(s[nt][0], s[nt][1]), fmaxf(s[nt][2], s[nt][3]));
      const float pmax = fmaxf(fmaxf(fmaxf(gm[0], gm[1]), fmaxf(gm[2], gm[3])),
                               fmaxf(fmaxf(gm[4], gm[5]), fmaxf(gm[6], gm[7])));

      // defer-max: only pay the reduce+rescale when the gap grows too large
      if (!__all(pmax <= m1 + DEFER_THR)) {
        float mr = fmaxf(pmax, __shfl_xor(pmax, 16));
        mr = fmaxf(mr, __shfl_xor(mr, 32));
        const float mnew = fmaxf(m1, mr);
        const float alpha = __builtin_amdgcn_exp2f(L2E8 * (m1 - mnew));
        m1 = mnew;
        l1 *= alpha;
        float ar[4];
#pragma unroll
        for (int r = 0; r < 4; r++) ar[r] = __shfl(alpha, (quad << 2) + r);
#pragma unroll
        for (int nt = 0; nt < 4; nt++)
#pragma unroll
          for (int r = 0; r < 4; r++) o[nt][r] *= ar[r];
      }

      // exp2 with folded 0.125*log2e; masked entries underflow to 0
      const float mb2 = L2E8 * m1;
#pragma unroll
      for (int nt = 0; nt < 8; nt++)
#pragma unroll
        for (int r = 0; r < 4; r++)
          s[nt][r] = __builtin_amdgcn_exp2f(L2E8 * s[nt][r] - mb2);
      {
        float gs[8];
#pragma unroll
        for (int nt = 0; nt < 8; nt++)
          gs[nt] = (s[nt][0] + s[nt][1]) + (s[nt][2] + s[nt][3]);
        l1 += ((gs[0] + gs[1]) + (gs[2] + gs[3])) +
              ((gs[4] + gs[5]) + (gs[6] + gs[7]));
      }

      // T12 per 64-half: P -> A-fragments in-register (cvt_pk + permlane32_swap)
      unsigned int A0, B0, A1, B1, A2, B2, A3, B3;
      union { unsigned int w[4]; bf16x8 v; } pa0u, pa1u, pa2u, pa3u;
      // half A: s[0..3]
      asm("v_cvt_pk_bf16_f32 %0, %1, %2" : "=v"(A0) : "v"(s[0][0]), "v"(s[0][1]));
      asm("v_cvt_pk_bf16_f32 %0, %1, %2" : "=v"(B0) : "v"(s[0][2]), "v"(s[0][3]));
      asm("v_cvt_pk_bf16_f32 %0, %1, %2" : "=v"(A1) : "v"(s[1][0]), "v"(s[1][1]));
      asm("v_cvt_pk_bf16_f32 %0, %1, %2" : "=v"(B1) : "v"(s[1][2]), "v"(s[1][3]));
      asm("v_cvt_pk_bf16_f32 %0, %1, %2" : "=v"(A2) : "v"(s[2][0]), "v"(s[2][1]));
      asm("v_cvt_pk_bf16_f32 %0, %1, %2" : "=v"(B2) : "v"(s[2][2]), "v"(s[2][3]));
      asm("v_cvt_pk_bf16_f32 %0, %1, %2" : "=v"(A3) : "v"(s[3][0]), "v"(s[3][1]));
      asm("v_cvt_pk_bf16_f32 %0, %1, %2" : "=v"(B3) : "v"(s[3][2]), "v"(s[3][3]));
      {
        const auto rA01 = __builtin_amdgcn_permlane32_swap(A0, A1, false, false);
        const auto rB01 = __builtin_amdgcn_permlane32_swap(B0, B1, false, false);
        const auto rA23 = __builtin_amdgcn_permlane32_swap(A2, A3, false, false);
        const auto rB23 = __builtin_amdgcn_permlane32_swap(B2, B3, false, false);
        pa0u.w[0] = rA01[0]; pa0u.w[1] = rB01[0];
        pa0u.w[2] = rA01[1]; pa0u.w[3] = rB01[1];
        pa1u.w[0] = rA23[0]; pa1u.w[1] = rB23[0];
        pa1u.w[2] = rA23[1]; pa1u.w[3] = rB23[1];
      }
      // half B: s[4..7]
      asm("v_cvt_pk_bf16_f32 %0, %1, %2" : "=v"(A0) : "v"(s[4][0]), "v"(s[4][1]));
      asm("v_cvt_pk_bf16_f32 %0, %1, %2" : "=v"(B0) : "v"(s[4][2]), "v"(s[4][3]));
      asm("v_cvt_pk_bf16_f32 %0, %1, %2" : "=v"(A1) : "v"(s[5][0]), "v"(s[5][1]));
      asm("v_cvt_pk_bf16_f32 %0, %1, %2" : "=v"(B1) : "v"(s[5][2]), "v"(s[5][3]));
      asm("v_cvt_pk_bf16_f32 %0, %1, %2" : "=v"(A2) : "v"(s[6][0]), "v"(s[6][1]));
      asm("v_cvt_pk_bf16_f32 %0, %1, %2" : "=v"(B2) : "v"(s[6][2]), "v"(s[6][3]));
      asm("v_cvt_pk_bf16_f32 %0, %1, %2" : "=v"(A3) : "v"(s[7][0]), "v"(s[7][1]));
      asm("v_cvt_pk_bf16_f32 %0, %1, %2" : "=v"(B3) : "v"(s[7][2]), "v"(s[7][3]));
      {
        const auto rA01 = __builtin_amdgcn_permlane32_swap(A0, A1, false, false);
        const auto rB01 = __builtin_amdgcn_permlane32_swap(B0, B1, false, false);
        const auto rA23 = __builtin_amdgcn_permlane32_swap(A2, A3, false, false);
        const auto rB23 = __builtin_amdgcn_permlane32_swap(B2, B3, false, false);
        pa2u.w[0] = rA01[0]; pa2u.w[1] = rB01[0];
        pa2u.w[2] = rA01[1]; pa2u.w[3] = rB01[1];
        pa3u.w[0] = rA23[0]; pa3u.w[1] = rB23[0];
        pa3u.w[2] = rA23[1]; pa3u.w[3] = rB23[1];
      }

      __builtin_amdgcn_s_setprio(1);
#pragma unroll
      for (int nt = 0; nt < 4; nt++) {
        const bf16x8 bvA0 = *(const bf16x8*)(&VbA[(nt * 16 + lo) * 64 + ck0]);
        const bf16x8 bvA1 = *(const bf16x8*)(&VbA[(nt * 16 + lo) * 64 + ck1]);
        const bf16x8 bvB0 = *(const bf16x8*)(&VbB[(nt * 16 + lo) * 64 + ck0]);
        const bf16x8 bvB1 = *(const bf16x8*)(&VbB[(nt * 16 + lo) * 64 + ck1]);
        o[nt] = __builtin_amdgcn_mfma_f32_16x16x32_bf16(pa0u.v, bvA0, o[nt], 0, 0, 0);
        o[nt] = __builtin_amdgcn_mfma_f32_16x16x32_bf16(pa1u.v, bvA1, o[nt], 0, 0, 0);
        o[nt] = __builtin_amdgcn_mfma_f32_16x16x32_bf16(pa2u.v, bvB0, o[nt], 0, 0, 0);
        o[nt] = __builtin_amdgcn_mfma_f32_16x16x32_bf16(pa3u.v, bvB1, o[nt], 0, 0, 0);
      }
      __builtin_amdgcn_s_setprio(0);

      // write prefetched V into the other buffer, then the SINGLE barrier
      if (hasnext) {
        const int nb = cur ^ 1;
#pragma unroll
        for (int hf = 0; hf < 2; hf++)
#pragma unroll
          for (int it = 0; it < 2; it++) {
            const int r = sr + it * 32;
            union { ushort8_t u; uint2v hh[2]; } vv;
            vv.u = vr[hf * 2 + it];
            *(uint2v*)&Vsh[nb * 2 * VH_W + hf * VH_W + r * 64 + vb0] = vv.hh[0];
            *(uint2v*)&Vsh[nb * 2 * VH_W + hf * VH_W + r * 64 + vb1] = vv.hh[1];
          }
      }
      __syncthreads();
      cur ^= 1;
    }

    // epilogue: reduce per-lane partial l across the 4 quads, transpose, write
    float lt = l1;
    lt += __shfl_xor(lt, 16);
    lt += __shfl_xor(lt, 32);
    const float linv = 1.f / lt;
    float ir[4];
#pragma unroll
    for (int r = 0; r < 4; r++) ir[r] = __shfl(linv, (quad << 2) + r);

#pragma unroll
    for (int nt = 0; nt < 4; nt++)
#pragma unroll
      for (int r = 0; r < 4; r++) {
        const int row = q0 + (wv << 4) + (quad << 2) + r;
        const int col = h * 64 + nt * 16 + lo;
        O[(size_t)(b * Tn + row) * Cn + col] = f2bf(o[nt][r] * ir[r]);
      }
  }
}

// ---------------------------------------------------------------------------
extern "C" void kernel_launch(void* const* d_in, const int* in_sizes, int n_in,
                              void* d_out, int out_size, void* d_ws, size_t ws_size,
                              hipStream_t stream) {
  const float* x    = (const float*)d_in[0];   // [B,T,C] fp32
  const float* Wqkv = (const float*)d_in[1];   // [C,3C] fp32
  const float* Wout = (const float*)d_in[2];   // [C,C] fp32
  float* out = (float*)d_out;                  // [B,T,C] fp32

  const size_t per = (size_t)Bn * Hn * Tn * Dn;     // 3,145,728 elems
  u16* xb    = (u16*)d_ws;                          // [4096,768] bf16
  u16* WqkvT = xb + (size_t)Mn * Cn;                // [2304,768] bf16
  u16* WoutT = WqkvT + (size_t)N3n * Cn;            // [768,768]  bf16
  u16* Qb    = WoutT + (size_t)Cn * Cn;             // [B,H,T,DH] bf16
  u16* Kb    = Qb + per;                            // [B,H,T,DH] bf16
  u16* VTb   = Kb + per;                            // [B,H,DH,T] bf16
  u16* attn  = VTb + per;                           // [B,T,C]    bf16
  int* counter = (int*)(attn + (size_t)Mn * Cn);    // [8] per-XCD counters
  // total ws use: ~36.2 MB (< 50.3 MB available)

  prep_kernel<<<dim3(3072 + 2304), 256, 0, stream>>>(x, Wqkv, Wout, xb, WqkvT,
                                                     WoutT, counter);
  mfma_gemm<0><<<dim3(N3n / 128, Mn / 128), 256, 0, stream>>>(xb, WqkvT, Qb, Kb, VTb, nullptr);
  attn_kernel<<<dim3(512), 256, 0, stream>>>(Qb, Kb, VTb, attn, counter);
  mfma_gemm<1><<<dim3(Cn / 128, Mn / 128), 256, 0, stream>>>(attn, WoutT, nullptr, nullptr, nullptr, out);
}